// Round 12
// baseline (106.975 us; speedup 1.0000x reference)
//
#include <hip/hip_runtime.h>

#define N_POINTS  131072
#define N_ANCHORS 2048
#define THREADS   256
#define PTS_BLK   256                       // points per block (16 tiles)
#define NBX       (N_POINTS / PTS_BLK)      // 512 point-blocks
#define MCHUNKS   4                         // anchor chunks -> 2048 blocks
#define NTILES_M  (N_ANCHORS / 16)          // 128 anchor tiles
#define TILES_PER (NTILES_M / MCHUNKS)      // 32 tiles per block
#define LOG2E     1.4426950408889634f

typedef __attribute__((ext_vector_type(8))) short  short8;   // 8 bf16 = MFMA A/B frag
typedef __attribute__((ext_vector_type(4))) float  f32x4;    // MFMA C/D frag

// ---------------------------------------------------------------------------
// Split-GEMM formulation (R9-verified):
//   arg(n,m) = q_m + r_m.x_n + sp_m*|x_n|^2  via mfma_f32_16x16x32_bf16,
// 3 bf16 limbs per f32, 27/32 K-slots, residual ~2^-27.
// R12: amortize per-iter overhead -- each wave holds 4 A-frags (64 points);
// per tile-iter: 1 B-load + 4 MFMA + 16 exp + 16 fma. Cross-round ledger
// showed exp-issue (33k cy/SIMD) + fma (8k) are irreducible; R11 spent an
// ADDITIONAL 21k on per-iter misc at 2 MFMAs/iter -- 4 MFMAs/iter halves it.
// ---------------------------------------------------------------------------

static __device__ __forceinline__ unsigned short f2bf(float v) {
    union { float f; unsigned u; } c; c.f = v;
    unsigned r = (c.u + 0x7FFFu + ((c.u >> 16) & 1u)) >> 16;   // RNE
    return (unsigned short)r;
}
static __device__ __forceinline__ float bf2f(unsigned short h) {
    union { unsigned u; float f; } c; c.u = ((unsigned)h) << 16;
    return c.f;
}
static __device__ __forceinline__ void split3(float v, unsigned short& h1,
                                              unsigned short& h2, unsigned short& h3) {
    h1 = f2bf(v); float v2 = v - bf2f(h1);
    h2 = f2bf(v2); float v3 = v2 - bf2f(h2);
    h3 = f2bf(v3);
}

#define BF_ONE ((short)0x3F80)

// ---------------------------------------------------------------------------
// prep_B: anchor-side fragments (unchanged layout since R9).
// ---------------------------------------------------------------------------
__global__ void prep_B(const float* __restrict__ aloc,
                       const float* __restrict__ coeffs,
                       const float* __restrict__ params,
                       short8* __restrict__ Bws,
                       float* __restrict__ cfws) {
    const int gid  = blockIdx.x * blockDim.x + threadIdx.x;   // [0, 8192)
    const int tile = gid >> 6;
    const int lane = gid & 63;
    const int kb   = lane >> 4;
    const int m    = tile * 16 + (lane & 15);

    const float a0 = aloc[3 * m + 0];
    const float a1 = aloc[3 * m + 1];
    const float a2 = aloc[3 * m + 2];
    const float w  = params[m];
    const float sp = -(0.5f * LOG2E) / (w * w);
    const float r0 = -2.0f * sp * a0;
    const float r1 = -2.0f * sp * a1;
    const float r2 = -2.0f * sp * a2;
    const float q  = sp * (a0 * a0 + a1 * a1 + a2 * a2);

    unsigned short r0a, r0b, r0c, r1a, r1b, r1c, r2a, r2b, r2c, spa, spb, spc, qa, qb, qc;
    split3(r0, r0a, r0b, r0c);
    split3(r1, r1a, r1b, r1c);
    split3(r2, r2a, r2b, r2c);
    split3(sp, spa, spb, spc);
    split3(q,  qa,  qb,  qc);

    short8 fr;
    switch (kb) {   // B-side limb pattern per group: {1,2,1,3,1,2}
    case 0: fr = (short8){(short)r0a,(short)r0b,(short)r0a,(short)r0c,(short)r0a,(short)r0b,(short)r1a,(short)r1b}; break;
    case 1: fr = (short8){(short)r1a,(short)r1c,(short)r1a,(short)r1b,(short)r2a,(short)r2b,(short)r2a,(short)r2c}; break;
    case 2: fr = (short8){(short)r2a,(short)r2b,(short)spa,(short)spb,(short)spa,(short)spc,(short)spa,(short)spb}; break;
    default:fr = (short8){(short)qa, (short)qb, (short)qc, 0, 0, 0, 0, 0}; break;
    }
    Bws[tile * 64 + lane] = fr;

    if (lane < 16) cfws[m] = coeffs[m];
}

// ---------------------------------------------------------------------------
// Main: grid (512, 4) x 256 thr = 2048 blocks = 8 blocks/CU (128 KB LDS/CU).
// Block stages 256 points (16 tiles); wave owns 4 tiles (64 points).
// Per tile-iter: 1 bf-load + 1 cf-load + 4 MFMA + 16 exp2 + 16 fma.
// ---------------------------------------------------------------------------
__global__ __launch_bounds__(256, 8) void lp_main(
    const float* __restrict__ xloc,
    const short8* __restrict__ Bws,
    const float* __restrict__ cfws,
    float* __restrict__ out)
{
    __shared__ short8 sA[16][64];    // 16 point-tiles x 64 lanes, 16 KiB

    const int t = threadIdx.x;

    // ---- stage this block's 256 points as A-fragments (1024 entries) ----
    #pragma unroll
    for (int e0 = 0; e0 < 4; ++e0) {
        const int e    = t + e0 * 256;
        const int tl   = e >> 6;
        const int lane = e & 63;
        const int kb   = lane >> 4;
        const int p    = blockIdx.x * PTS_BLK + tl * 16 + (lane & 15);

        const float x = xloc[3 * p + 0];
        const float y = xloc[3 * p + 1];
        const float z = xloc[3 * p + 2];
        const float ss = fmaf(x, x, fmaf(y, y, z * z));

        unsigned short xa, xb, xc, ya, yb, yc, za, zb, zc, sa, sb, sc;
        split3(x,  xa, xb, xc);
        split3(y,  ya, yb, yc);
        split3(z,  za, zb, zc);
        split3(ss, sa, sb, sc);

        short8 fr;
        switch (kb) {   // A-side limb pattern per group: {1,1,2,1,3,2}
        case 0: fr = (short8){(short)xa,(short)xa,(short)xb,(short)xa,(short)xc,(short)xb,(short)ya,(short)ya}; break;
        case 1: fr = (short8){(short)yb,(short)ya,(short)yc,(short)yb,(short)za,(short)za,(short)zb,(short)za}; break;
        case 2: fr = (short8){(short)zc,(short)zb,(short)sa,(short)sa,(short)sb,(short)sa,(short)sc,(short)sb}; break;
        default:fr = (short8){BF_ONE, BF_ONE, BF_ONE, 0, 0, 0, 0, 0}; break;
        }
        sA[tl][lane] = fr;
    }
    __syncthreads();

    const int wave = t >> 6;
    const int lane = t & 63;
    const int col  = lane & 15;

    const short8 a0 = sA[wave * 4 + 0][lane];
    const short8 a1 = sA[wave * 4 + 1][lane];
    const short8 a2 = sA[wave * 4 + 2][lane];
    const short8 a3 = sA[wave * 4 + 3][lane];

    f32x4 acc0 = {0.f, 0.f, 0.f, 0.f};
    f32x4 acc1 = {0.f, 0.f, 0.f, 0.f};
    f32x4 acc2 = {0.f, 0.f, 0.f, 0.f};
    f32x4 acc3 = {0.f, 0.f, 0.f, 0.f};
    const f32x4 cz = {0.f, 0.f, 0.f, 0.f};

    const int tm0 = blockIdx.y * TILES_PER;

    #pragma unroll 2
    for (int tt = 0; tt < TILES_PER; ++tt) {
        const int tm = tm0 + tt;
        const short8 bf = Bws[tm * 64 + lane];
        const float  cf = cfws[tm * 16 + col];

        f32x4 c0 = __builtin_amdgcn_mfma_f32_16x16x32_bf16(a0, bf, cz, 0, 0, 0);
        f32x4 c1 = __builtin_amdgcn_mfma_f32_16x16x32_bf16(a1, bf, cz, 0, 0, 0);
        f32x4 c2 = __builtin_amdgcn_mfma_f32_16x16x32_bf16(a2, bf, cz, 0, 0, 0);
        f32x4 c3 = __builtin_amdgcn_mfma_f32_16x16x32_bf16(a3, bf, cz, 0, 0, 0);

        #pragma unroll
        for (int r = 0; r < 4; ++r) {
            acc0[r] = fmaf(cf, __builtin_amdgcn_exp2f(c0[r]), acc0[r]);
            acc1[r] = fmaf(cf, __builtin_amdgcn_exp2f(c1[r]), acc1[r]);
            acc2[r] = fmaf(cf, __builtin_amdgcn_exp2f(c2[r]), acc2[r]);
            acc3[r] = fmaf(cf, __builtin_amdgcn_exp2f(c3[r]), acc3[r]);
        }
    }

    // ---- reduce over the 16 anchor-col lanes of each group ----
    #pragma unroll
    for (int o = 1; o < 16; o <<= 1) {
        #pragma unroll
        for (int r = 0; r < 4; ++r) {
            acc0[r] += __shfl_xor(acc0[r], o, 16);
            acc1[r] += __shfl_xor(acc1[r], o, 16);
            acc2[r] += __shfl_xor(acc2[r], o, 16);
            acc3[r] += __shfl_xor(acc3[r], o, 16);
        }
    }

    if (col == 0) {
        const int kb = lane >> 4;
        const int pb = blockIdx.x * PTS_BLK + wave * 64 + kb * 4;
        #pragma unroll
        for (int r = 0; r < 4; ++r) {
            atomicAdd(&out[pb +  0 + r], acc0[r]);
            atomicAdd(&out[pb + 16 + r], acc1[r]);
            atomicAdd(&out[pb + 32 + r], acc2[r]);
            atomicAdd(&out[pb + 48 + r], acc3[r]);
        }
    }
}

extern "C" void kernel_launch(void* const* d_in, const int* in_sizes, int n_in,
                              void* d_out, int out_size, void* d_ws, size_t ws_size,
                              hipStream_t stream) {
    const float* xloc   = (const float*)d_in[0];   // [131072,3]
    const float* aloc   = (const float*)d_in[1];   // [2048,3]
    const float* coeffs = (const float*)d_in[2];   // [2048]
    const float* params = (const float*)d_in[3];   // [2048]
    float* out = (float*)d_out;                    // [131072] f32

    short8* Bws = (short8*)d_ws;                                   // 128 KiB
    float*  cfws = (float*)((char*)d_ws + NTILES_M * 64 * sizeof(short8)); // +8 KiB

    // out accumulates 4 partials per element -> zero it (poisoned 0xAA).
    hipMemsetAsync(d_out, 0, N_POINTS * sizeof(float), stream);

    prep_B<<<dim3((NTILES_M * 64) / THREADS), dim3(THREADS), 0, stream>>>(
        aloc, coeffs, params, Bws, cfws);

    lp_main<<<dim3(NBX, MCHUNKS), dim3(THREADS), 0, stream>>>(
        xloc, Bws, cfws, out);
}

// Round 13
// 93.103 us; speedup vs baseline: 1.1490x; 1.1490x over previous
//
#include <hip/hip_runtime.h>

#define N_POINTS  131072
#define N_ANCHORS 2048
#define THREADS   512                      // 8 waves per block
#define PTS_BLK   256                      // points per block (16 tiles)
#define NBLOCKS   (N_POINTS / PTS_BLK)     // 512 blocks = 2 blocks/CU = 8 w/SIMD
#define NTILES_M  (N_ANCHORS / 16)         // 128 anchor tiles
#define LOG2E     1.4426950408889634f

typedef __attribute__((ext_vector_type(8))) short  short8;   // 8 bf16 = MFMA A/B frag
typedef __attribute__((ext_vector_type(4))) float  f32x4;    // MFMA C/D frag

// ---------------------------------------------------------------------------
// Split-GEMM formulation (R9-verified, absmax identical to scalar):
//   arg(n,m) = q_m + r_m.x_n + sp_m*|x_n|^2  via mfma_f32_16x16x32_bf16,
// 3 bf16 limbs per f32, 27/32 K-slots, residual ~2^-27.
// R13 = R9's per-wave structure (2 A-frags, 1 B-load per 2 MFMAs, full anchor
// range, direct stores -- the minimal-busy point of the R9-R12 ledger) at
// 8 waves/SIMD via 512-thread blocks (512 blocks = exactly 2 blocks/CU).
// No atomics, no memset, no anchor split.
// ---------------------------------------------------------------------------

static __device__ __forceinline__ unsigned short f2bf(float v) {
    union { float f; unsigned u; } c; c.f = v;
    unsigned r = (c.u + 0x7FFFu + ((c.u >> 16) & 1u)) >> 16;   // RNE
    return (unsigned short)r;
}
static __device__ __forceinline__ float bf2f(unsigned short h) {
    union { unsigned u; float f; } c; c.u = ((unsigned)h) << 16;
    return c.f;
}
static __device__ __forceinline__ void split3(float v, unsigned short& h1,
                                              unsigned short& h2, unsigned short& h3) {
    h1 = f2bf(v); float v2 = v - bf2f(h1);
    h2 = f2bf(v2); float v3 = v2 - bf2f(h2);
    h3 = f2bf(v3);
}

#define BF_ONE ((short)0x3F80)

// ---------------------------------------------------------------------------
// prep_B: anchor-side fragments (unchanged layout since R9).
// ---------------------------------------------------------------------------
__global__ void prep_B(const float* __restrict__ aloc,
                       const float* __restrict__ coeffs,
                       const float* __restrict__ params,
                       short8* __restrict__ Bws,
                       float* __restrict__ cfws) {
    const int gid  = blockIdx.x * blockDim.x + threadIdx.x;   // [0, 8192)
    const int tile = gid >> 6;
    const int lane = gid & 63;
    const int kb   = lane >> 4;
    const int m    = tile * 16 + (lane & 15);

    const float a0 = aloc[3 * m + 0];
    const float a1 = aloc[3 * m + 1];
    const float a2 = aloc[3 * m + 2];
    const float w  = params[m];
    const float sp = -(0.5f * LOG2E) / (w * w);
    const float r0 = -2.0f * sp * a0;
    const float r1 = -2.0f * sp * a1;
    const float r2 = -2.0f * sp * a2;
    const float q  = sp * (a0 * a0 + a1 * a1 + a2 * a2);

    unsigned short r0a, r0b, r0c, r1a, r1b, r1c, r2a, r2b, r2c, spa, spb, spc, qa, qb, qc;
    split3(r0, r0a, r0b, r0c);
    split3(r1, r1a, r1b, r1c);
    split3(r2, r2a, r2b, r2c);
    split3(sp, spa, spb, spc);
    split3(q,  qa,  qb,  qc);

    short8 fr;
    switch (kb) {   // B-side limb pattern per group: {1,2,1,3,1,2}
    case 0: fr = (short8){(short)r0a,(short)r0b,(short)r0a,(short)r0c,(short)r0a,(short)r0b,(short)r1a,(short)r1b}; break;
    case 1: fr = (short8){(short)r1a,(short)r1c,(short)r1a,(short)r1b,(short)r2a,(short)r2b,(short)r2a,(short)r2c}; break;
    case 2: fr = (short8){(short)r2a,(short)r2b,(short)spa,(short)spb,(short)spa,(short)spc,(short)spa,(short)spb}; break;
    default:fr = (short8){(short)qa, (short)qb, (short)qc, 0, 0, 0, 0, 0}; break;
    }
    Bws[tile * 64 + lane] = fr;

    if (lane < 16) cfws[m] = coeffs[m];
}

// ---------------------------------------------------------------------------
// Main: 512 blocks x 512 thr (8 waves) = 2 blocks/CU = 8 waves/SIMD.
// Block stages 256 points (16 tiles, 1024 frag entries, 2 per thread);
// wave owns 2 tiles (32 points); loops ALL 128 anchor tiles:
// per iter 1 bf-load + 1 cf-load + 2 MFMA + 8 exp2 + 8 fma. Direct stores.
// ---------------------------------------------------------------------------
__global__ __launch_bounds__(512, 4) void lp_main(
    const float* __restrict__ xloc,
    const short8* __restrict__ Bws,
    const float* __restrict__ cfws,
    float* __restrict__ out)
{
    __shared__ short8 sA[16][64];    // 16 point-tiles x 64 lanes, 16 KiB

    const int t = threadIdx.x;

    // ---- stage this block's 256 points as A-fragments (1024 entries) ----
    #pragma unroll
    for (int e0 = 0; e0 < 2; ++e0) {
        const int e    = t + e0 * 512;
        const int tl   = e >> 6;
        const int lane = e & 63;
        const int kb   = lane >> 4;
        const int p    = blockIdx.x * PTS_BLK + tl * 16 + (lane & 15);

        const float x = xloc[3 * p + 0];
        const float y = xloc[3 * p + 1];
        const float z = xloc[3 * p + 2];
        const float ss = fmaf(x, x, fmaf(y, y, z * z));

        unsigned short xa, xb, xc, ya, yb, yc, za, zb, zc, sa, sb, sc;
        split3(x,  xa, xb, xc);
        split3(y,  ya, yb, yc);
        split3(z,  za, zb, zc);
        split3(ss, sa, sb, sc);

        short8 fr;
        switch (kb) {   // A-side limb pattern per group: {1,1,2,1,3,2}
        case 0: fr = (short8){(short)xa,(short)xa,(short)xb,(short)xa,(short)xc,(short)xb,(short)ya,(short)ya}; break;
        case 1: fr = (short8){(short)yb,(short)ya,(short)yc,(short)yb,(short)za,(short)za,(short)zb,(short)za}; break;
        case 2: fr = (short8){(short)zc,(short)zb,(short)sa,(short)sa,(short)sb,(short)sa,(short)sc,(short)sb}; break;
        default:fr = (short8){BF_ONE, BF_ONE, BF_ONE, 0, 0, 0, 0, 0}; break;
        }
        sA[tl][lane] = fr;
    }
    __syncthreads();

    const int wave = t >> 6;          // 0..7
    const int lane = t & 63;
    const int col  = lane & 15;

    const short8 a0 = sA[wave * 2 + 0][lane];
    const short8 a1 = sA[wave * 2 + 1][lane];

    f32x4 acc0 = {0.f, 0.f, 0.f, 0.f};
    f32x4 acc1 = {0.f, 0.f, 0.f, 0.f};
    const f32x4 cz = {0.f, 0.f, 0.f, 0.f};

    #pragma unroll 2
    for (int tm = 0; tm < NTILES_M; ++tm) {
        const short8 bf = Bws[tm * 64 + lane];
        const float  cf = cfws[tm * 16 + col];

        f32x4 c0 = __builtin_amdgcn_mfma_f32_16x16x32_bf16(a0, bf, cz, 0, 0, 0);
        f32x4 c1 = __builtin_amdgcn_mfma_f32_16x16x32_bf16(a1, bf, cz, 0, 0, 0);

        #pragma unroll
        for (int r = 0; r < 4; ++r) {
            acc0[r] = fmaf(cf, __builtin_amdgcn_exp2f(c0[r]), acc0[r]);
            acc1[r] = fmaf(cf, __builtin_amdgcn_exp2f(c1[r]), acc1[r]);
        }
    }

    // ---- reduce over the 16 anchor-col lanes of each group ----
    #pragma unroll
    for (int o = 1; o < 16; o <<= 1) {
        #pragma unroll
        for (int r = 0; r < 4; ++r) {
            acc0[r] += __shfl_xor(acc0[r], o, 16);
            acc1[r] += __shfl_xor(acc1[r], o, 16);
        }
    }

    if (col == 0) {
        const int kb = lane >> 4;
        const int pb = blockIdx.x * PTS_BLK + wave * 32;
        #pragma unroll
        for (int r = 0; r < 4; ++r) {
            out[pb +      kb * 4 + r] = acc0[r];
            out[pb + 16 + kb * 4 + r] = acc1[r];
        }
    }
}

extern "C" void kernel_launch(void* const* d_in, const int* in_sizes, int n_in,
                              void* d_out, int out_size, void* d_ws, size_t ws_size,
                              hipStream_t stream) {
    const float* xloc   = (const float*)d_in[0];   // [131072,3]
    const float* aloc   = (const float*)d_in[1];   // [2048,3]
    const float* coeffs = (const float*)d_in[2];   // [2048]
    const float* params = (const float*)d_in[3];   // [2048]
    float* out = (float*)d_out;                    // [131072] f32

    short8* Bws = (short8*)d_ws;                                   // 128 KiB
    float*  cfws = (float*)((char*)d_ws + NTILES_M * 64 * sizeof(short8)); // +8 KiB

    prep_B<<<dim3((NTILES_M * 64) / 256), dim3(256), 0, stream>>>(
        aloc, coeffs, params, Bws, cfws);

    lp_main<<<dim3(NBLOCKS), dim3(THREADS), 0, stream>>>(
        xloc, Bws, cfws, out);
}